// Round 1
// baseline (396.432 us; speedup 1.0000x reference)
//
#include <hip/hip_runtime.h>
#include <hip/hip_bf16.h>

typedef __attribute__((ext_vector_type(8))) short v8s;
typedef __attribute__((ext_vector_type(4))) short v4s;
typedef __attribute__((ext_vector_type(4))) float v4f;
typedef __attribute__((ext_vector_type(8))) float v8f;

#define NB 4
#define NN 4096
#define ND 256
#define NH 4
#define NHD 64

__device__ __forceinline__ short f2bs(float f) {
  union { __hip_bfloat16 h; short s; } u;
  u.h = __float2bfloat16(f);
  return u.s;
}
__device__ __forceinline__ float bs2f(short s) {
  union { short s; __hip_bfloat16 h; } u;
  u.s = s;
  return __bfloat162float(u.h);
}

// ---------------- K0: cast descriptors fp32 -> bf16 into hbuf[:, 0:256] (ld 512)
__global__ void k_cast(const float* __restrict__ desc, short* __restrict__ hbuf) {
  int i = blockIdx.x * blockDim.x + threadIdx.x;   // one float4 per thread
  const v4f* src = (const v4f*)desc;
  v4f v = src[i];
  int e0 = i << 2;
  int row = e0 >> 8;
  int col = e0 & 255;
  v4s o;
  #pragma unroll
  for (int j = 0; j < 4; ++j) o[j] = f2bs(v[j]);
  *(v4s*)(hbuf + row * 512 + col) = o;
}

// ---------------- K1: QKV GEMM (M=16384,K=256,N=768), scatter into Q/K/V [B,H,N,hd]
__global__ __launch_bounds__(256)
void k_qkv(const short* __restrict__ hbuf, const float* __restrict__ W,
           const float* __restrict__ bias, short* __restrict__ Qb,
           short* __restrict__ Kb, short* __restrict__ Vb) {
  __shared__ short Al[64 * 32];
  __shared__ short Bl[64 * 32];
  int mt = blockIdx.x, nt = blockIdx.y, tid = threadIdx.x;
  int w = tid >> 6, lane = tid & 63, lg = lane >> 4, lr = lane & 15;
  int srow = tid >> 2, scol8 = (tid & 3) << 3;
  v4f acc[4] = {};
  for (int kt = 0; kt < 8; ++kt) {
    int k0 = kt * 32;
    v8s av = *(const v8s*)(hbuf + (size_t)(mt * 64 + srow) * 512 + k0 + scol8);
    v8f wv = *(const v8f*)(W + (size_t)(nt * 64 + srow) * 256 + k0 + scol8);
    v8s bv;
    #pragma unroll
    for (int i = 0; i < 8; ++i) bv[i] = f2bs(wv[i]);
    __syncthreads();
    *(v8s*)(Al + srow * 32 + (scol8 ^ ((srow & 3) << 3))) = av;
    *(v8s*)(Bl + srow * 32 + (scol8 ^ ((srow & 3) << 3))) = bv;
    __syncthreads();
    int ar = w * 16 + lr;
    v8s af = *(const v8s*)(Al + ar * 32 + ((lg * 8) ^ ((ar & 3) << 3)));
    #pragma unroll
    for (int c = 0; c < 4; ++c) {
      int br = c * 16 + lr;
      v8s bf = *(const v8s*)(Bl + br * 32 + ((lg * 8) ^ ((br & 3) << 3)));
      acc[c] = __builtin_amdgcn_mfma_f32_16x16x32_bf16(af, bf, acc[c], 0, 0, 0);
    }
  }
  #pragma unroll
  for (int c = 0; c < 4; ++c) {
    int gcol = nt * 64 + c * 16 + lr;           // 0..767
    float bb = bias[gcol];
    int h_ = gcol / 192;
    int rem = gcol - h_ * 192;
    int d_ = rem / 3;
    int t_ = rem - d_ * 3;
    short* dst = (t_ == 0) ? Qb : ((t_ == 1) ? Kb : Vb);
    #pragma unroll
    for (int j = 0; j < 4; ++j) {
      int grow = mt * 64 + w * 16 + lg * 4 + j;  // b*N+n
      int b_ = grow >> 12, n_ = grow & 4095;
      dst[(size_t)((b_ * NH + h_) * NN + n_) * NHD + d_] = f2bs(acc[c][j] + bb);
    }
  }
}

// ---------------- K2: RoPE in-place on Q (with 1/8 scale) and K
__global__ void k_rope(short* __restrict__ Qb, short* __restrict__ Kb,
                       const float* __restrict__ kp) {
  int idx = blockIdx.x * blockDim.x + threadIdx.x;   // [0, 2*B*H*N*32)
  const int half = NB * NH * NN * 32;
  short* buf = (idx < half) ? Qb : Kb;
  float sc = (idx < half) ? 0.125f : 1.0f;
  int p = (idx < half) ? idx : idx - half;
  int i = p & 31;
  int row = p >> 5;            // b*H*N + h*N + n
  int bh = row >> 12;
  int n = row & 4095;
  int b = bh >> 2;
  const float* cosp = kp + (size_t)((0 * NB + b) * NN + n) * NHD;
  const float* sinp = kp + (size_t)((1 * NB + b) * NN + n) * NHD;
  int d0 = 2 * i;
  float c0 = cosp[d0], c1 = cosp[d0 + 1], s0 = sinp[d0], s1 = sinp[d0 + 1];
  short* xp = buf + (size_t)row * NHD + d0;
  float x0 = bs2f(xp[0]), x1 = bs2f(xp[1]);
  xp[0] = f2bs((x0 * c0 - x1 * s0) * sc);
  xp[1] = f2bs((x1 * c1 + x0 * s1) * sc);
}

// ---------------- K3: flash attention. grid (N/64, B*H), 4 waves.
__global__ __launch_bounds__(256)
void k_attn(const short* __restrict__ Qb, const short* __restrict__ Kb,
            const short* __restrict__ Vb, short* __restrict__ ctx) {
  __shared__ short Kl[64 * 64];
  __shared__ short Vt[64 * 64];
  __shared__ short Pl[4 * 16 * 64];
  int qt = blockIdx.x, bh = blockIdx.y;
  int b = bh >> 2, h = bh & 3;
  const short* Qp = Qb + (size_t)bh * NN * NHD;
  const short* Kp = Kb + (size_t)bh * NN * NHD;
  const short* Vp = Vb + (size_t)bh * NN * NHD;
  int tid = threadIdx.x, w = tid >> 6, lane = tid & 63, lg = lane >> 4, lr = lane & 15;
  int qrow = qt * 64 + w * 16 + lr;
  v8s qf0 = *(const v8s*)(Qp + (size_t)qrow * 64 + lg * 8);
  v8s qf1 = *(const v8s*)(Qp + (size_t)qrow * 64 + 32 + lg * 8);
  float m[4], l[4];
  #pragma unroll
  for (int j = 0; j < 4; ++j) { m[j] = -3.0e38f; l[j] = 0.f; }
  v4f acc[4] = {};
  int skey = tid >> 2, sd16 = (tid & 3) << 4;
  for (int kt = 0; kt < 64; ++kt) {
    const short* kp = Kp + (size_t)(kt * 64 + skey) * 64 + sd16;
    const short* vp = Vp + (size_t)(kt * 64 + skey) * 64 + sd16;
    v8s kv0 = *(const v8s*)kp;
    v8s kv1 = *(const v8s*)(kp + 8);
    v8s vv0 = *(const v8s*)vp;
    v8s vv1 = *(const v8s*)(vp + 8);
    __syncthreads();   // previous iteration's reads done
    *(v8s*)(Kl + skey * 64 + ((sd16)     ^ ((skey & 7) << 3))) = kv0;
    *(v8s*)(Kl + skey * 64 + ((sd16 + 8) ^ ((skey & 7) << 3))) = kv1;
    #pragma unroll
    for (int i = 0; i < 8; ++i) {
      int d0 = sd16 + i;
      Vt[d0 * 64 + (skey ^ ((d0 & 7) << 3))] = vv0[i];
      int d1 = sd16 + 8 + i;
      Vt[d1 * 64 + (skey ^ ((d1 & 7) << 3))] = vv1[i];
    }
    __syncthreads();
    // S = Q K^T  (scale folded into Q)
    v4f sc4[4] = {};
    #pragma unroll
    for (int c = 0; c < 4; ++c) {
      int kr = c * 16 + lr;
      v8s kf0 = *(const v8s*)(Kl + kr * 64 + ((lg * 8)      ^ ((kr & 7) << 3)));
      sc4[c] = __builtin_amdgcn_mfma_f32_16x16x32_bf16(qf0, kf0, sc4[c], 0, 0, 0);
      v8s kf1 = *(const v8s*)(Kl + kr * 64 + ((32 + lg * 8) ^ ((kr & 7) << 3)));
      sc4[c] = __builtin_amdgcn_mfma_f32_16x16x32_bf16(qf1, kf1, sc4[c], 0, 0, 0);
    }
    // online softmax (rows = lg*4+j, cols across lane&15 and chunks)
    float tm[4];
    #pragma unroll
    for (int j = 0; j < 4; ++j)
      tm[j] = fmaxf(fmaxf(sc4[0][j], sc4[1][j]), fmaxf(sc4[2][j], sc4[3][j]));
    #pragma unroll
    for (int mk = 1; mk < 16; mk <<= 1) {
      #pragma unroll
      for (int j = 0; j < 4; ++j) tm[j] = fmaxf(tm[j], __shfl_xor(tm[j], mk, 64));
    }
    float rr_[4];
    #pragma unroll
    for (int j = 0; j < 4; ++j) {
      float mn = fmaxf(m[j], tm[j]);
      rr_[j] = __expf(m[j] - mn);
      m[j] = mn;
    }
    float p[4][4], ps[4];
    #pragma unroll
    for (int j = 0; j < 4; ++j) ps[j] = 0.f;
    #pragma unroll
    for (int c = 0; c < 4; ++c) {
      #pragma unroll
      for (int j = 0; j < 4; ++j) {
        p[c][j] = __expf(sc4[c][j] - m[j]);
        ps[j] += p[c][j];
      }
    }
    #pragma unroll
    for (int mk = 1; mk < 16; mk <<= 1) {
      #pragma unroll
      for (int j = 0; j < 4; ++j) ps[j] += __shfl_xor(ps[j], mk, 64);
    }
    #pragma unroll
    for (int j = 0; j < 4; ++j) l[j] = l[j] * rr_[j] + ps[j];
    #pragma unroll
    for (int oc = 0; oc < 4; ++oc) {
      #pragma unroll
      for (int j = 0; j < 4; ++j) acc[oc][j] *= rr_[j];
    }
    int wb = w * 1024;
    #pragma unroll
    for (int c = 0; c < 4; ++c) {
      #pragma unroll
      for (int j = 0; j < 4; ++j) {
        int row = lg * 4 + j;
        Pl[wb + row * 64 + ((c * 16 + lr) ^ ((row & 7) << 3))] = f2bs(p[c][j]);
      }
    }
    __syncthreads();   // P visible within wave-group; Vt stable
    #pragma unroll
    for (int s = 0; s < 2; ++s) {
      v8s pf = *(const v8s*)(Pl + wb + lr * 64 + ((s * 32 + lg * 8) ^ ((lr & 7) << 3)));
      #pragma unroll
      for (int oc = 0; oc < 4; ++oc) {
        int dr = oc * 16 + lr;
        v8s vf = *(const v8s*)(Vt + dr * 64 + ((s * 32 + lg * 8) ^ ((dr & 7) << 3)));
        acc[oc] = __builtin_amdgcn_mfma_f32_16x16x32_bf16(pf, vf, acc[oc], 0, 0, 0);
      }
    }
  }
  #pragma unroll
  for (int oc = 0; oc < 4; ++oc) {
    #pragma unroll
    for (int j = 0; j < 4; ++j) {
      int row = w * 16 + lg * 4 + j;
      int n = qt * 64 + row;
      float v = acc[oc][j] / l[j];
      ctx[(size_t)(b * NN + n) * ND + h * NHD + oc * 16 + lr] = f2bs(v);
    }
  }
}

// ---------------- K4: out-proj GEMM (M=16384,K=256,N=256) -> hbuf[:, 256:512]
__global__ __launch_bounds__(256)
void k_oproj(const short* __restrict__ ctx, const float* __restrict__ W,
             const float* __restrict__ bias, short* __restrict__ hbuf) {
  __shared__ short Al[64 * 32];
  __shared__ short Bl[64 * 32];
  int mt = blockIdx.x, nt = blockIdx.y, tid = threadIdx.x;
  int w = tid >> 6, lane = tid & 63, lg = lane >> 4, lr = lane & 15;
  int srow = tid >> 2, scol8 = (tid & 3) << 3;
  v4f acc[4] = {};
  for (int kt = 0; kt < 8; ++kt) {
    int k0 = kt * 32;
    v8s av = *(const v8s*)(ctx + (size_t)(mt * 64 + srow) * 256 + k0 + scol8);
    v8f wv = *(const v8f*)(W + (size_t)(nt * 64 + srow) * 256 + k0 + scol8);
    v8s bv;
    #pragma unroll
    for (int i = 0; i < 8; ++i) bv[i] = f2bs(wv[i]);
    __syncthreads();
    *(v8s*)(Al + srow * 32 + (scol8 ^ ((srow & 3) << 3))) = av;
    *(v8s*)(Bl + srow * 32 + (scol8 ^ ((srow & 3) << 3))) = bv;
    __syncthreads();
    int ar = w * 16 + lr;
    v8s af = *(const v8s*)(Al + ar * 32 + ((lg * 8) ^ ((ar & 3) << 3)));
    #pragma unroll
    for (int c = 0; c < 4; ++c) {
      int br = c * 16 + lr;
      v8s bf = *(const v8s*)(Bl + br * 32 + ((lg * 8) ^ ((br & 3) << 3)));
      acc[c] = __builtin_amdgcn_mfma_f32_16x16x32_bf16(af, bf, acc[c], 0, 0, 0);
    }
  }
  #pragma unroll
  for (int c = 0; c < 4; ++c) {
    int gcol = nt * 64 + c * 16 + lr;
    float bb = bias[gcol];
    #pragma unroll
    for (int j = 0; j < 4; ++j) {
      int grow = mt * 64 + w * 16 + lg * 4 + j;
      hbuf[(size_t)grow * 512 + 256 + gcol] = f2bs(acc[c][j] + bb);
    }
  }
}

// ---------------- K5: ffn1 GEMM (M=16384,K=512,N=512) + bias + LN + GELU -> h2 bf16
__global__ __launch_bounds__(256)
void k_ffn1(const short* __restrict__ hbuf, const float* __restrict__ W,
            const float* __restrict__ bias, const float* __restrict__ ln_g,
            const float* __restrict__ ln_b, short* __restrict__ h2) {
  __shared__ short Al[64 * 32];
  __shared__ short Bl[512 * 32];
  int mt = blockIdx.x, tid = threadIdx.x;
  int w = tid >> 6, lane = tid & 63, lg = lane >> 4, lr = lane & 15;
  int srow = tid >> 2, scol8 = (tid & 3) << 3;
  v4f acc[32] = {};
  for (int kt = 0; kt < 16; ++kt) {
    int k0 = kt * 32;
    v8s av = *(const v8s*)(hbuf + (size_t)(mt * 64 + srow) * 512 + k0 + scol8);
    v8s bvs[8];
    #pragma unroll
    for (int rr = 0; rr < 8; ++rr) {
      v8f wv = *(const v8f*)(W + (size_t)(srow + rr * 64) * 512 + k0 + scol8);
      #pragma unroll
      for (int i = 0; i < 8; ++i) bvs[rr][i] = f2bs(wv[i]);
    }
    __syncthreads();
    *(v8s*)(Al + srow * 32 + (scol8 ^ ((srow & 3) << 3))) = av;
    #pragma unroll
    for (int rr = 0; rr < 8; ++rr) {
      int br = srow + rr * 64;
      *(v8s*)(Bl + br * 32 + (scol8 ^ ((br & 3) << 3))) = bvs[rr];
    }
    __syncthreads();
    int ar = w * 16 + lr;
    v8s af = *(const v8s*)(Al + ar * 32 + ((lg * 8) ^ ((ar & 3) << 3)));
    #pragma unroll
    for (int c = 0; c < 32; ++c) {
      int br = c * 16 + lr;
      v8s bf = *(const v8s*)(Bl + br * 32 + ((lg * 8) ^ ((br & 3) << 3)));
      acc[c] = __builtin_amdgcn_mfma_f32_16x16x32_bf16(af, bf, acc[c], 0, 0, 0);
    }
  }
  // bias
  #pragma unroll
  for (int c = 0; c < 32; ++c) {
    float bb = bias[c * 16 + lr];
    #pragma unroll
    for (int j = 0; j < 4; ++j) acc[c][j] += bb;
  }
  // LayerNorm over 512 (each wave owns its 16 rows fully)
  float mu[4], rs[4];
  #pragma unroll
  for (int j = 0; j < 4; ++j) {
    float s = 0.f;
    #pragma unroll
    for (int c = 0; c < 32; ++c) s += acc[c][j];
    #pragma unroll
    for (int mk = 1; mk < 16; mk <<= 1) s += __shfl_xor(s, mk, 64);
    mu[j] = s * (1.0f / 512.0f);
  }
  #pragma unroll
  for (int j = 0; j < 4; ++j) {
    float s = 0.f;
    #pragma unroll
    for (int c = 0; c < 32; ++c) { float d = acc[c][j] - mu[j]; s += d * d; }
    #pragma unroll
    for (int mk = 1; mk < 16; mk <<= 1) s += __shfl_xor(s, mk, 64);
    rs[j] = rsqrtf(s * (1.0f / 512.0f) + 1e-5f);
  }
  #pragma unroll
  for (int c = 0; c < 32; ++c) {
    int col = c * 16 + lr;
    float g = ln_g[col], b2 = ln_b[col];
    #pragma unroll
    for (int j = 0; j < 4; ++j) {
      float y = (acc[c][j] - mu[j]) * rs[j] * g + b2;
      float ge = 0.5f * y * (1.0f + erff(y * 0.70710678118654752f));
      int grow = mt * 64 + w * 16 + lg * 4 + j;
      h2[(size_t)grow * 512 + col] = f2bs(ge);
    }
  }
}

// ---------------- K6: ffn2 GEMM (M=16384,K=512,N=256) + bias + residual -> out fp32
__global__ __launch_bounds__(256)
void k_ffn2(const short* __restrict__ h2, const float* __restrict__ W,
            const float* __restrict__ bias, const float* __restrict__ desc,
            float* __restrict__ out) {
  __shared__ short Al[64 * 32];
  __shared__ short Bl[64 * 32];
  int mt = blockIdx.x, nt = blockIdx.y, tid = threadIdx.x;
  int w = tid >> 6, lane = tid & 63, lg = lane >> 4, lr = lane & 15;
  int srow = tid >> 2, scol8 = (tid & 3) << 3;
  v4f acc[4] = {};
  for (int kt = 0; kt < 16; ++kt) {
    int k0 = kt * 32;
    v8s av = *(const v8s*)(h2 + (size_t)(mt * 64 + srow) * 512 + k0 + scol8);
    v8f wv = *(const v8f*)(W + (size_t)(nt * 64 + srow) * 512 + k0 + scol8);
    v8s bv;
    #pragma unroll
    for (int i = 0; i < 8; ++i) bv[i] = f2bs(wv[i]);
    __syncthreads();
    *(v8s*)(Al + srow * 32 + (scol8 ^ ((srow & 3) << 3))) = av;
    *(v8s*)(Bl + srow * 32 + (scol8 ^ ((srow & 3) << 3))) = bv;
    __syncthreads();
    int ar = w * 16 + lr;
    v8s af = *(const v8s*)(Al + ar * 32 + ((lg * 8) ^ ((ar & 3) << 3)));
    #pragma unroll
    for (int c = 0; c < 4; ++c) {
      int br = c * 16 + lr;
      v8s bf = *(const v8s*)(Bl + br * 32 + ((lg * 8) ^ ((br & 3) << 3)));
      acc[c] = __builtin_amdgcn_mfma_f32_16x16x32_bf16(af, bf, acc[c], 0, 0, 0);
    }
  }
  #pragma unroll
  for (int c = 0; c < 4; ++c) {
    int gcol = nt * 64 + c * 16 + lr;
    float bb = bias[gcol];
    #pragma unroll
    for (int j = 0; j < 4; ++j) {
      int grow = mt * 64 + w * 16 + lg * 4 + j;
      out[(size_t)grow * 256 + gcol] = desc[(size_t)grow * 256 + gcol] + acc[c][j] + bb;
    }
  }
}

extern "C" void kernel_launch(void* const* d_in, const int* in_sizes, int n_in,
                              void* d_out, int out_size, void* d_ws, size_t ws_size,
                              hipStream_t stream) {
  const float* desc   = (const float*)d_in[0];
  const float* kp     = (const float*)d_in[1];
  const float* Wqkv_w = (const float*)d_in[2];
  const float* Wqkv_b = (const float*)d_in[3];
  const float* out_w  = (const float*)d_in[4];
  const float* out_b  = (const float*)d_in[5];
  const float* ffn1_w = (const float*)d_in[6];
  const float* ffn1_b = (const float*)d_in[7];
  const float* ln_g   = (const float*)d_in[8];
  const float* ln_b   = (const float*)d_in[9];
  const float* ffn2_w = (const float*)d_in[10];
  const float* ffn2_b = (const float*)d_in[11];
  float* out = (float*)d_out;
  char* ws = (char*)d_ws;

  const size_t MB = 1024 * 1024;
  short* hbuf = (short*)(ws);                 // [16384][512] bf16 : 16MB (desc | message)
  short* Qb   = (short*)(ws + 16 * MB);       // [B,H,N,64] bf16 : 8MB
  short* Kb   = (short*)(ws + 24 * MB);       // 8MB
  short* Vb   = (short*)(ws + 32 * MB);       // 8MB
  short* ctxb = (short*)(ws + 40 * MB);       // [16384][256] bf16 : 8MB
  short* h2   = (short*)(ws + 16 * MB);       // [16384][512] bf16 : reuses Q/K (dead after attn)

  k_cast <<<dim3(4096),      dim3(256), 0, stream>>>(desc, hbuf);
  k_qkv  <<<dim3(256, 12),   dim3(256), 0, stream>>>(hbuf, Wqkv_w, Wqkv_b, Qb, Kb, Vb);
  k_rope <<<dim3(16384),     dim3(256), 0, stream>>>(Qb, Kb, kp);
  k_attn <<<dim3(64, 16),    dim3(256), 0, stream>>>(Qb, Kb, Vb, ctxb);
  k_oproj<<<dim3(256, 4),    dim3(256), 0, stream>>>(ctxb, out_w, out_b, hbuf);
  k_ffn1 <<<dim3(256),       dim3(256), 0, stream>>>(hbuf, ffn1_w, ffn1_b, ln_g, ln_b, h2);
  k_ffn2 <<<dim3(256, 4),    dim3(256), 0, stream>>>(h2, ffn2_w, ffn2_b, desc, out);
}

// Round 2
// 294.071 us; speedup vs baseline: 1.3481x; 1.3481x over previous
//
#include <hip/hip_runtime.h>
#include <hip/hip_bf16.h>

typedef __attribute__((ext_vector_type(8))) short v8s;
typedef __attribute__((ext_vector_type(4))) short v4s;
typedef __attribute__((ext_vector_type(4))) float v4f;
typedef __attribute__((ext_vector_type(8))) float v8f;

#define NB 4
#define NN 4096
#define ND 256
#define NH 4
#define NHD 64

__device__ __forceinline__ short f2bs(float f) {
  union { __hip_bfloat16 h; short s; } u;
  u.h = __float2bfloat16(f);
  return u.s;
}
__device__ __forceinline__ float bs2f(short s) {
  union { short s; __hip_bfloat16 h; } u;
  u.s = s;
  return __bfloat162float(u.h);
}

__device__ __forceinline__ void gload16(const short* g, short* l) {
  __builtin_amdgcn_global_load_lds((const __attribute__((address_space(1))) void*)g,
                                   (__attribute__((address_space(3))) void*)l, 16, 0, 0);
}

// ---------------- K0: cast descriptors fp32 -> bf16 into hbuf[:, 0:256] (ld 512)
__global__ void k_cast(const float* __restrict__ desc, short* __restrict__ hbuf) {
  int i = blockIdx.x * blockDim.x + threadIdx.x;   // one float4 per thread
  const v4f* src = (const v4f*)desc;
  v4f v = src[i];
  int e0 = i << 2;
  int row = e0 >> 8;
  int col = e0 & 255;
  v4s o;
  #pragma unroll
  for (int j = 0; j < 4; ++j) o[j] = f2bs(v[j]);
  *(v4s*)(hbuf + row * 512 + col) = o;
}

// ---------------- K1: QKV GEMM (M=16384,K=256,N=768); Q,K scatter [B,H,N,64]; V transposed [B,H,64,N]
__global__ __launch_bounds__(256)
void k_qkv(const short* __restrict__ hbuf, const float* __restrict__ W,
           const float* __restrict__ bias, short* __restrict__ Qb,
           short* __restrict__ Kb, short* __restrict__ Vt) {
  __shared__ short Al[64 * 32];
  __shared__ short Bl[64 * 32];
  int mt = blockIdx.x, nt = blockIdx.y, tid = threadIdx.x;
  int w = tid >> 6, lane = tid & 63, lg = lane >> 4, lr = lane & 15;
  int srow = tid >> 2, scol8 = (tid & 3) << 3;
  v4f acc[4] = {};
  for (int kt = 0; kt < 8; ++kt) {
    int k0 = kt * 32;
    v8s av = *(const v8s*)(hbuf + (size_t)(mt * 64 + srow) * 512 + k0 + scol8);
    v8f wv = *(const v8f*)(W + (size_t)(nt * 64 + srow) * 256 + k0 + scol8);
    v8s bv;
    #pragma unroll
    for (int i = 0; i < 8; ++i) bv[i] = f2bs(wv[i]);
    __syncthreads();
    *(v8s*)(Al + srow * 32 + (scol8 ^ ((srow & 3) << 3))) = av;
    *(v8s*)(Bl + srow * 32 + (scol8 ^ ((srow & 3) << 3))) = bv;
    __syncthreads();
    int ar = w * 16 + lr;
    v8s af = *(const v8s*)(Al + ar * 32 + ((lg * 8) ^ ((ar & 3) << 3)));
    #pragma unroll
    for (int c = 0; c < 4; ++c) {
      int br = c * 16 + lr;
      v8s bf = *(const v8s*)(Bl + br * 32 + ((lg * 8) ^ ((br & 3) << 3)));
      acc[c] = __builtin_amdgcn_mfma_f32_16x16x32_bf16(af, bf, acc[c], 0, 0, 0);
    }
  }
  #pragma unroll
  for (int c = 0; c < 4; ++c) {
    int gcol = nt * 64 + c * 16 + lr;           // 0..767
    float bb = bias[gcol];
    int h_ = gcol / 192;
    int rem = gcol - h_ * 192;
    int d_ = rem / 3;
    int t_ = rem - d_ * 3;
    int grow0 = mt * 64 + w * 16 + lg * 4;       // j=0 row (b*N+n), 4-aligned
    int b_ = grow0 >> 12, n0 = grow0 & 4095;
    if (t_ == 2) {
      v4s pw;
      #pragma unroll
      for (int j = 0; j < 4; ++j) pw[j] = f2bs(acc[c][j] + bb);
      *(v4s*)(Vt + ((size_t)((b_ * NH + h_) * NHD + d_) * NN + n0)) = pw;
    } else {
      short* dst = (t_ == 0) ? Qb : Kb;
      #pragma unroll
      for (int j = 0; j < 4; ++j) {
        dst[(size_t)((b_ * NH + h_) * NN + n0 + j) * NHD + d_] = f2bs(acc[c][j] + bb);
      }
    }
  }
}

// ---------------- K2: RoPE in-place on Q (with 0.125*log2e scale) and K
__global__ void k_rope(short* __restrict__ Qb, short* __restrict__ Kb,
                       const float* __restrict__ kp) {
  int idx = blockIdx.x * blockDim.x + threadIdx.x;   // [0, 2*B*H*N*32)
  const int half = NB * NH * NN * 32;
  short* buf = (idx < half) ? Qb : Kb;
  float sc = (idx < half) ? 0.125f * 1.44269504088896340736f : 1.0f;
  int p = (idx < half) ? idx : idx - half;
  int i = p & 31;
  int row = p >> 5;            // b*H*N + h*N + n
  int bh = row >> 12;
  int n = row & 4095;
  int b = bh >> 2;
  const float* cosp = kp + (size_t)((0 * NB + b) * NN + n) * NHD;
  const float* sinp = kp + (size_t)((1 * NB + b) * NN + n) * NHD;
  int d0 = 2 * i;
  float c0 = cosp[d0], c1 = cosp[d0 + 1], s0 = sinp[d0], s1 = sinp[d0 + 1];
  short* xp = buf + (size_t)row * NHD + d0;
  float x0 = bs2f(xp[0]), x1 = bs2f(xp[1]);
  xp[0] = f2bs((x0 * c0 - x1 * s0) * sc);
  xp[1] = f2bs((x1 * c1 + x0 * s1) * sc);
}

// ---------------- K3: flash attention v2. grid (N/64, B*H), 4 waves.
// K,Vt staged via global_load_lds (pre-swizzled source); swapped QK^T (S^T in regs);
// packed P writes; double-buffered staging with counted vmcnt.
__global__ __launch_bounds__(256)
void k_attn(const short* __restrict__ Qb, const short* __restrict__ Kb,
            const short* __restrict__ Vt, short* __restrict__ ctx) {
  __shared__ short Kl[2][4096];   // [buf][row64 x chunk8 x 8elems] swizzled
  __shared__ short Vl[2][4096];   // [buf][d64 x chunk8 x 8elems] swizzled
  __shared__ short Pl[4][1024];   // per-wave [q16][kv64] swizzled
  int qt = blockIdx.x, bh = blockIdx.y;
  int b = bh >> 2, h = bh & 3;
  const short* Qp = Qb + (size_t)bh * NN * NHD;
  const short* Kp = Kb + (size_t)bh * NN * NHD;
  const short* Vp = Vt + (size_t)bh * NHD * NN;   // [64][4096]
  int tid = threadIdx.x, w = tid >> 6, lane = tid & 63, lg = lane >> 4, lr = lane & 15;
  // Q fragment (B-operand of swapped QK^T): q = qt*64 + w*16 + lr, d = lg*8 (+32)
  int qrow = qt * 64 + w * 16 + lr;
  v8s qf0 = *(const v8s*)(Qp + (size_t)qrow * 64 + lg * 8);
  v8s qf1 = *(const v8s*)(Qp + (size_t)qrow * 64 + 32 + lg * 8);
  float m = -3.0e38f, lsum = 0.f;
  v4f acc[4] = {};
  // staging geometry: 512 16B-slots per tile; wave w covers slots w*128..w*128+127 (2 issues)
  int slot0 = w * 128 + lane;
  int slot1 = slot0 + 64;
  int r0 = slot0 >> 3, c0 = slot0 & 7;
  int r1 = slot1 >> 3, c1 = slot1 & 7;
  int ko0 = r0 * 64 + ((c0 ^ (r0 & 7)) << 3);
  int ko1 = r1 * 64 + ((c1 ^ (r1 & 7)) << 3);
  size_t vo0 = (size_t)r0 * NN + ((c0 ^ (r0 & 7)) << 3);
  size_t vo1 = (size_t)r1 * NN + ((c1 ^ (r1 & 7)) << 3);

  #define STAGE(t, bf) do { \
    const short* Kt_ = Kp + (t) * 4096; \
    gload16(Kt_ + ko0, &Kl[bf][w * 1024]); \
    gload16(Kt_ + ko1, &Kl[bf][w * 1024 + 512]); \
    const short* Vt_ = Vp + (t) * 64; \
    gload16(Vt_ + vo0, &Vl[bf][w * 1024]); \
    gload16(Vt_ + vo1, &Vl[bf][w * 1024 + 512]); \
  } while (0)

  STAGE(0, 0);
  for (int kt = 0; kt < 64; ++kt) {
    int bf = kt & 1;
    if (kt < 63) {
      STAGE(kt + 1, bf ^ 1);
      asm volatile("s_waitcnt vmcnt(4)" ::: "memory");
    } else {
      asm volatile("s_waitcnt vmcnt(0)" ::: "memory");
    }
    __builtin_amdgcn_s_barrier();
    __builtin_amdgcn_sched_barrier(0);
    const short* Kb_ = Kl[bf];
    const short* Vb_ = Vl[bf];
    // S^T = K · Q^T : per c-block, D[kv=lg*4+j][q=lr]
    v4f st[4] = {};
    __builtin_amdgcn_s_setprio(1);
    #pragma unroll
    for (int c = 0; c < 4; ++c) {
      int kr = c * 16 + lr;
      v8s kf0 = *(const v8s*)(Kb_ + kr * 64 + ((lg ^ (kr & 7)) << 3));
      v8s kf1 = *(const v8s*)(Kb_ + kr * 64 + (((lg + 4) ^ (kr & 7)) << 3));
      st[c] = __builtin_amdgcn_mfma_f32_16x16x32_bf16(kf0, qf0, st[c], 0, 0, 0);
      st[c] = __builtin_amdgcn_mfma_f32_16x16x32_bf16(kf1, qf1, st[c], 0, 0, 0);
    }
    __builtin_amdgcn_s_setprio(0);
    // online softmax in log2 domain; lane owns q=lr, 16 kv vals (c,j); reduce over lg groups
    float pmax = st[0][0];
    #pragma unroll
    for (int c = 0; c < 4; ++c)
      #pragma unroll
      for (int j = 0; j < 4; ++j) pmax = fmaxf(pmax, st[c][j]);
    pmax = fmaxf(pmax, __shfl_xor(pmax, 16, 64));
    pmax = fmaxf(pmax, __shfl_xor(pmax, 32, 64));
    float mn = fmaxf(m, pmax);
    float rr = exp2f(m - mn);
    m = mn;
    float ps = 0.f;
    float pb[4][4];
    #pragma unroll
    for (int c = 0; c < 4; ++c) {
      #pragma unroll
      for (int j = 0; j < 4; ++j) {
        pb[c][j] = exp2f(st[c][j] - m);
        ps += pb[c][j];
      }
    }
    ps += __shfl_xor(ps, 16, 64);
    ps += __shfl_xor(ps, 32, 64);
    lsum = lsum * rr + ps;
    // write P (wave-local, swizzled): row lr, elems c*16+lg*4 .. +3
    #pragma unroll
    for (int c = 0; c < 4; ++c) {
      v4s pw;
      #pragma unroll
      for (int j = 0; j < 4; ++j) pw[j] = f2bs(pb[c][j]);
      int o = c * 16 + lg * 4;
      int chunk = o >> 3, halfo = o & 7;
      *(v4s*)(&Pl[w][lr * 64 + ((chunk ^ (lr & 7)) << 3) + halfo]) = pw;
    }
    // rescale acc (acc rows are q = lg*4+j; rr lives at lane lr=q)
    float rq[4];
    #pragma unroll
    for (int j = 0; j < 4; ++j) rq[j] = __shfl(rr, lg * 4 + j, 16);
    #pragma unroll
    for (int oc = 0; oc < 4; ++oc)
      #pragma unroll
      for (int j = 0; j < 4; ++j) acc[oc][j] *= rq[j];
    // PV: A = P (row q=lr loc), B = V (col d); Vl holds V^T rows d
    __builtin_amdgcn_s_setprio(1);
    #pragma unroll
    for (int s = 0; s < 2; ++s) {
      v8s pf = *(const v8s*)(&Pl[w][lr * 64 + (((s * 4 + lg) ^ (lr & 7)) << 3)]);
      #pragma unroll
      for (int oc = 0; oc < 4; ++oc) {
        int dr = oc * 16 + lr;
        v8s vf = *(const v8s*)(Vb_ + dr * 64 + (((s * 4 + lg) ^ (dr & 7)) << 3));
        acc[oc] = __builtin_amdgcn_mfma_f32_16x16x32_bf16(pf, vf, acc[oc], 0, 0, 0);
      }
    }
    __builtin_amdgcn_s_setprio(0);
    __builtin_amdgcn_s_barrier();
    __builtin_amdgcn_sched_barrier(0);
  }
  #undef STAGE
  float lq[4];
  #pragma unroll
  for (int j = 0; j < 4; ++j) lq[j] = __shfl(lsum, lg * 4 + j, 16);
  #pragma unroll
  for (int oc = 0; oc < 4; ++oc) {
    #pragma unroll
    for (int j = 0; j < 4; ++j) {
      int n = qt * 64 + w * 16 + lg * 4 + j;
      ctx[(size_t)(b * NN + n) * ND + h * NHD + oc * 16 + lr] = f2bs(acc[oc][j] / lq[j]);
    }
  }
}

// ---------------- K4: out-proj GEMM (M=16384,K=256,N=256) -> hbuf[:, 256:512]
__global__ __launch_bounds__(256)
void k_oproj(const short* __restrict__ ctx, const float* __restrict__ W,
             const float* __restrict__ bias, short* __restrict__ hbuf) {
  __shared__ short Al[64 * 32];
  __shared__ short Bl[64 * 32];
  int mt = blockIdx.x, nt = blockIdx.y, tid = threadIdx.x;
  int w = tid >> 6, lane = tid & 63, lg = lane >> 4, lr = lane & 15;
  int srow = tid >> 2, scol8 = (tid & 3) << 3;
  v4f acc[4] = {};
  for (int kt = 0; kt < 8; ++kt) {
    int k0 = kt * 32;
    v8s av = *(const v8s*)(ctx + (size_t)(mt * 64 + srow) * 256 + k0 + scol8);
    v8f wv = *(const v8f*)(W + (size_t)(nt * 64 + srow) * 256 + k0 + scol8);
    v8s bv;
    #pragma unroll
    for (int i = 0; i < 8; ++i) bv[i] = f2bs(wv[i]);
    __syncthreads();
    *(v8s*)(Al + srow * 32 + (scol8 ^ ((srow & 3) << 3))) = av;
    *(v8s*)(Bl + srow * 32 + (scol8 ^ ((srow & 3) << 3))) = bv;
    __syncthreads();
    int ar = w * 16 + lr;
    v8s af = *(const v8s*)(Al + ar * 32 + ((lg * 8) ^ ((ar & 3) << 3)));
    #pragma unroll
    for (int c = 0; c < 4; ++c) {
      int br = c * 16 + lr;
      v8s bf = *(const v8s*)(Bl + br * 32 + ((lg * 8) ^ ((br & 3) << 3)));
      acc[c] = __builtin_amdgcn_mfma_f32_16x16x32_bf16(af, bf, acc[c], 0, 0, 0);
    }
  }
  #pragma unroll
  for (int c = 0; c < 4; ++c) {
    int gcol = nt * 64 + c * 16 + lr;
    float bb = bias[gcol];
    #pragma unroll
    for (int j = 0; j < 4; ++j) {
      int grow = mt * 64 + w * 16 + lg * 4 + j;
      hbuf[(size_t)grow * 512 + 256 + gcol] = f2bs(acc[c][j] + bb);
    }
  }
}

// ---------------- K5: ffn1 GEMM (M=16384,K=512,N=512) + bias + LN + GELU -> h2 bf16
__global__ __launch_bounds__(256)
void k_ffn1(const short* __restrict__ hbuf, const float* __restrict__ W,
            const float* __restrict__ bias, const float* __restrict__ ln_g,
            const float* __restrict__ ln_b, short* __restrict__ h2) {
  __shared__ short Al[64 * 32];
  __shared__ short Bl[512 * 32];
  int mt = blockIdx.x, tid = threadIdx.x;
  int w = tid >> 6, lane = tid & 63, lg = lane >> 4, lr = lane & 15;
  int srow = tid >> 2, scol8 = (tid & 3) << 3;
  v4f acc[32] = {};
  for (int kt = 0; kt < 16; ++kt) {
    int k0 = kt * 32;
    v8s av = *(const v8s*)(hbuf + (size_t)(mt * 64 + srow) * 512 + k0 + scol8);
    v8s bvs[8];
    #pragma unroll
    for (int rr = 0; rr < 8; ++rr) {
      v8f wv = *(const v8f*)(W + (size_t)(srow + rr * 64) * 512 + k0 + scol8);
      #pragma unroll
      for (int i = 0; i < 8; ++i) bvs[rr][i] = f2bs(wv[i]);
    }
    __syncthreads();
    *(v8s*)(Al + srow * 32 + (scol8 ^ ((srow & 3) << 3))) = av;
    #pragma unroll
    for (int rr = 0; rr < 8; ++rr) {
      int br = srow + rr * 64;
      *(v8s*)(Bl + br * 32 + (scol8 ^ ((br & 3) << 3))) = bvs[rr];
    }
    __syncthreads();
    int ar = w * 16 + lr;
    v8s af = *(const v8s*)(Al + ar * 32 + ((lg * 8) ^ ((ar & 3) << 3)));
    #pragma unroll
    for (int c = 0; c < 32; ++c) {
      int br = c * 16 + lr;
      v8s bf = *(const v8s*)(Bl + br * 32 + ((lg * 8) ^ ((br & 3) << 3)));
      acc[c] = __builtin_amdgcn_mfma_f32_16x16x32_bf16(af, bf, acc[c], 0, 0, 0);
    }
  }
  #pragma unroll
  for (int c = 0; c < 32; ++c) {
    float bb = bias[c * 16 + lr];
    #pragma unroll
    for (int j = 0; j < 4; ++j) acc[c][j] += bb;
  }
  float mu[4], rs[4];
  #pragma unroll
  for (int j = 0; j < 4; ++j) {
    float s = 0.f;
    #pragma unroll
    for (int c = 0; c < 32; ++c) s += acc[c][j];
    #pragma unroll
    for (int mk = 1; mk < 16; mk <<= 1) s += __shfl_xor(s, mk, 64);
    mu[j] = s * (1.0f / 512.0f);
  }
  #pragma unroll
  for (int j = 0; j < 4; ++j) {
    float s = 0.f;
    #pragma unroll
    for (int c = 0; c < 32; ++c) { float d = acc[c][j] - mu[j]; s += d * d; }
    #pragma unroll
    for (int mk = 1; mk < 16; mk <<= 1) s += __shfl_xor(s, mk, 64);
    rs[j] = rsqrtf(s * (1.0f / 512.0f) + 1e-5f);
  }
  #pragma unroll
  for (int c = 0; c < 32; ++c) {
    int col = c * 16 + lr;
    float g = ln_g[col], b2 = ln_b[col];
    #pragma unroll
    for (int j = 0; j < 4; ++j) {
      float y = (acc[c][j] - mu[j]) * rs[j] * g + b2;
      float ge = 0.5f * y * (1.0f + erff(y * 0.70710678118654752f));
      int grow = mt * 64 + w * 16 + lg * 4 + j;
      h2[(size_t)grow * 512 + col] = f2bs(ge);
    }
  }
}

// ---------------- K6: ffn2 GEMM (M=16384,K=512,N=256) + bias + residual -> out fp32
__global__ __launch_bounds__(256)
void k_ffn2(const short* __restrict__ h2, const float* __restrict__ W,
            const float* __restrict__ bias, const float* __restrict__ desc,
            float* __restrict__ out) {
  __shared__ short Al[64 * 32];
  __shared__ short Bl[64 * 32];
  int mt = blockIdx.x, nt = blockIdx.y, tid = threadIdx.x;
  int w = tid >> 6, lane = tid & 63, lg = lane >> 4, lr = lane & 15;
  int srow = tid >> 2, scol8 = (tid & 3) << 3;
  v4f acc[4] = {};
  for (int kt = 0; kt < 16; ++kt) {
    int k0 = kt * 32;
    v8s av = *(const v8s*)(h2 + (size_t)(mt * 64 + srow) * 512 + k0 + scol8);
    v8f wv = *(const v8f*)(W + (size_t)(nt * 64 + srow) * 512 + k0 + scol8);
    v8s bv;
    #pragma unroll
    for (int i = 0; i < 8; ++i) bv[i] = f2bs(wv[i]);
    __syncthreads();
    *(v8s*)(Al + srow * 32 + (scol8 ^ ((srow & 3) << 3))) = av;
    *(v8s*)(Bl + srow * 32 + (scol8 ^ ((srow & 3) << 3))) = bv;
    __syncthreads();
    int ar = w * 16 + lr;
    v8s af = *(const v8s*)(Al + ar * 32 + ((lg * 8) ^ ((ar & 3) << 3)));
    #pragma unroll
    for (int c = 0; c < 4; ++c) {
      int br = c * 16 + lr;
      v8s bf = *(const v8s*)(Bl + br * 32 + ((lg * 8) ^ ((br & 3) << 3)));
      acc[c] = __builtin_amdgcn_mfma_f32_16x16x32_bf16(af, bf, acc[c], 0, 0, 0);
    }
  }
  #pragma unroll
  for (int c = 0; c < 4; ++c) {
    int gcol = nt * 64 + c * 16 + lr;
    float bb = bias[gcol];
    #pragma unroll
    for (int j = 0; j < 4; ++j) {
      int grow = mt * 64 + w * 16 + lg * 4 + j;
      out[(size_t)grow * 256 + gcol] = desc[(size_t)grow * 256 + gcol] + acc[c][j] + bb;
    }
  }
}

extern "C" void kernel_launch(void* const* d_in, const int* in_sizes, int n_in,
                              void* d_out, int out_size, void* d_ws, size_t ws_size,
                              hipStream_t stream) {
  const float* desc   = (const float*)d_in[0];
  const float* kp     = (const float*)d_in[1];
  const float* Wqkv_w = (const float*)d_in[2];
  const float* Wqkv_b = (const float*)d_in[3];
  const float* out_w  = (const float*)d_in[4];
  const float* out_b  = (const float*)d_in[5];
  const float* ffn1_w = (const float*)d_in[6];
  const float* ffn1_b = (const float*)d_in[7];
  const float* ln_g   = (const float*)d_in[8];
  const float* ln_b   = (const float*)d_in[9];
  const float* ffn2_w = (const float*)d_in[10];
  const float* ffn2_b = (const float*)d_in[11];
  float* out = (float*)d_out;
  char* ws = (char*)d_ws;

  const size_t MB = 1024 * 1024;
  short* hbuf = (short*)(ws);                 // [16384][512] bf16 : 16MB (desc | message)
  short* Qb   = (short*)(ws + 16 * MB);       // [B,H,N,64] bf16 : 8MB
  short* Kb   = (short*)(ws + 24 * MB);       // 8MB
  short* Vt   = (short*)(ws + 32 * MB);       // [B,H,64,N] bf16 : 8MB (transposed V)
  short* ctxb = (short*)(ws + 40 * MB);       // [16384][256] bf16 : 8MB
  short* h2   = (short*)(ws + 16 * MB);       // [16384][512] bf16 : reuses Q/K (dead after attn)

  k_cast <<<dim3(4096),      dim3(256), 0, stream>>>(desc, hbuf);
  k_qkv  <<<dim3(256, 12),   dim3(256), 0, stream>>>(hbuf, Wqkv_w, Wqkv_b, Qb, Kb, Vt);
  k_rope <<<dim3(16384),     dim3(256), 0, stream>>>(Qb, Kb, kp);
  k_attn <<<dim3(64, 16),    dim3(256), 0, stream>>>(Qb, Kb, Vt, ctxb);
  k_oproj<<<dim3(256, 4),    dim3(256), 0, stream>>>(ctxb, out_w, out_b, hbuf);
  k_ffn1 <<<dim3(256),       dim3(256), 0, stream>>>(hbuf, ffn1_w, ffn1_b, ln_g, ln_b, h2);
  k_ffn2 <<<dim3(256, 4),    dim3(256), 0, stream>>>(h2, ffn2_w, ffn2_b, desc, out);
}

// Round 3
// 216.728 us; speedup vs baseline: 1.8292x; 1.3569x over previous
//
#include <hip/hip_runtime.h>
#include <hip/hip_bf16.h>

typedef __attribute__((ext_vector_type(8))) short v8s;
typedef __attribute__((ext_vector_type(4))) short v4s;
typedef __attribute__((ext_vector_type(4))) float v4f;
typedef __attribute__((ext_vector_type(8))) float v8f;

#define NB 4
#define NN 4096
#define ND 256
#define NH 4
#define NHD 64

__device__ __forceinline__ short f2bs(float f) {
  union { __hip_bfloat16 h; short s; } u;
  u.h = __float2bfloat16(f);
  return u.s;
}
// fast RNE-ish bf16 pack (no NaN path; values bounded in our use)
__device__ __forceinline__ short f2bs_fast(float f) {
  unsigned u = __float_as_uint(f);
  return (short)((u + 0x7fffu + ((u >> 16) & 1u)) >> 16);
}
__device__ __forceinline__ float fexp2(float x) {
#if __has_builtin(__builtin_amdgcn_exp2f)
  return __builtin_amdgcn_exp2f(x);
#else
  return exp2f(x);
#endif
}

__device__ __forceinline__ void gload16(const short* g, short* l) {
  __builtin_amdgcn_global_load_lds((const __attribute__((address_space(1))) void*)g,
                                   (__attribute__((address_space(3))) void*)l, 16, 0, 0);
}

// ---------------- K0: cast descriptors fp32 -> bf16 into hbuf[:, 0:256] (ld 512)
__global__ void k_cast(const float* __restrict__ desc, short* __restrict__ hbuf) {
  int i = blockIdx.x * blockDim.x + threadIdx.x;   // one float4 per thread
  const v4f* src = (const v4f*)desc;
  v4f v = src[i];
  int e0 = i << 2;
  int row = e0 >> 8;
  int col = e0 & 255;
  v4s o;
  #pragma unroll
  for (int j = 0; j < 4; ++j) o[j] = f2bs(v[j]);
  *(v4s*)(hbuf + row * 512 + col) = o;
}

// ---------------- K0b: cast weights fp32 -> bf16 (Wqkv | out_w | ffn1_w | ffn2_w)
__global__ void k_wcast(const float* __restrict__ a, const float* __restrict__ b,
                        const float* __restrict__ c, const float* __restrict__ d,
                        short* __restrict__ o) {
  int i = (blockIdx.x * 256 + threadIdx.x) * 8;
  const float* s; int off;
  if (i < 196608)      { s = a; off = 0; }
  else if (i < 262144) { s = b; off = 196608; }
  else if (i < 524288) { s = c; off = 262144; }
  else                 { s = d; off = 524288; }
  v8f v = *(const v8f*)(s + (i - off));
  v8s r;
  #pragma unroll
  for (int j = 0; j < 8; ++j) r[j] = f2bs(v[j]);
  *(v8s*)(o + i) = r;
}

// ---------------- K1: QKV GEMM (M=16384,K=256, 768 outputs in PERMUTED col order) + fused RoPE
// virtual col vc in [0,768): t=vc>>8 (0=Q,1=K,2=V), h=(vc&255)>>6, d=vc&63; W row = h*192+3d+t.
// grid.y=nt in [0,12): t=nt>>2 (block-uniform), h=nt&3. Q,K -> [B,H,N,64] with RoPE; V -> [B,H,64,N].
__global__ __launch_bounds__(256)
void k_qkv(const short* __restrict__ hbuf, const short* __restrict__ Wb,
           const float* __restrict__ bias, const float* __restrict__ kp,
           short* __restrict__ Qb, short* __restrict__ Kb, short* __restrict__ Vt) {
  __shared__ short Al[64 * 32];
  __shared__ short Bl[64 * 32];
  int mt = blockIdx.x, nt = blockIdx.y, tid = threadIdx.x;
  int w = tid >> 6, lane = tid & 63, lg = lane >> 4, lr = lane & 15;
  int srow = tid >> 2, scol8 = (tid & 3) << 3;
  int t_ = nt >> 2, h_ = nt & 3;
  // permuted W row for this staging thread's virtual col
  int dS = (nt * 64 + srow) & 63;
  int wrow = h_ * 192 + dS * 3 + t_;
  v4f acc[4] = {};
  for (int kt = 0; kt < 8; ++kt) {
    int k0 = kt * 32;
    v8s av = *(const v8s*)(hbuf + (size_t)(mt * 64 + srow) * 512 + k0 + scol8);
    v8s bv = *(const v8s*)(Wb + (size_t)wrow * 256 + k0 + scol8);
    __syncthreads();
    *(v8s*)(Al + srow * 32 + (scol8 ^ ((srow & 3) << 3))) = av;
    *(v8s*)(Bl + srow * 32 + (scol8 ^ ((srow & 3) << 3))) = bv;
    __syncthreads();
    int ar = w * 16 + lr;
    v8s af = *(const v8s*)(Al + ar * 32 + ((lg * 8) ^ ((ar & 3) << 3)));
    #pragma unroll
    for (int c = 0; c < 4; ++c) {
      int br = c * 16 + lr;
      v8s bf = *(const v8s*)(Bl + br * 32 + ((lg * 8) ^ ((br & 3) << 3)));
      acc[c] = __builtin_amdgcn_mfma_f32_16x16x32_bf16(af, bf, acc[c], 0, 0, 0);
    }
  }
  int grow0 = mt * 64 + w * 16 + lg * 4;
  int b_ = grow0 >> 12, n0 = grow0 & 4095;
  if (t_ == 2) {
    #pragma unroll
    for (int c = 0; c < 4; ++c) {
      int d = c * 16 + lr;
      float bb = bias[h_ * 192 + d * 3 + 2];
      v4s pw;
      #pragma unroll
      for (int j = 0; j < 4; ++j) pw[j] = f2bs(acc[c][j] + bb);
      *(v4s*)(Vt + ((size_t)((b_ * NH + h_) * NHD + d) * NN + n0)) = pw;
    }
  } else {
    float qsc = (t_ == 0) ? 0.125f * 1.44269504088896340736f : 1.0f;
    short* dst = (t_ == 0) ? Qb : Kb;
    #pragma unroll
    for (int c = 0; c < 4; ++c) {
      int d = c * 16 + lr;
      float bb = bias[h_ * 192 + d * 3 + t_];
      #pragma unroll
      for (int j = 0; j < 4; ++j) {
        float x = acc[c][j] + bb;
        float xp = __shfl_xor(x, 1, 64);   // partner of the rotary pair (d^1)
        int n_ = n0 + j;
        float cs = kp[((size_t)b_ * NN + n_) * 64 + d];
        float sn = kp[((size_t)(NB + b_) * NN + n_) * 64 + d];
        float ov = (d & 1) ? (x * cs + xp * sn) : (x * cs - xp * sn);
        dst[((size_t)((b_ * NH + h_) * NN + n_)) * 64 + d] = f2bs(ov * qsc);
      }
    }
  }
}

// ---------------- K3: flash attention v3. grid (N/64, B*H), 4 waves.
__global__ __launch_bounds__(256)
void k_attn(const short* __restrict__ Qb, const short* __restrict__ Kb,
            const short* __restrict__ Vt, short* __restrict__ ctx) {
  __shared__ short Kl[2][4096];
  __shared__ short Vl[2][4096];
  __shared__ short Pl[4][1024];
  int qt = blockIdx.x, bh = blockIdx.y;
  int b = bh >> 2, h = bh & 3;
  const short* Qp = Qb + (size_t)bh * NN * NHD;
  const short* Kp = Kb + (size_t)bh * NN * NHD;
  const short* Vp = Vt + (size_t)bh * NHD * NN;
  int tid = threadIdx.x, w = tid >> 6, lane = tid & 63, lg = lane >> 4, lr = lane & 15;
  int qrow = qt * 64 + w * 16 + lr;
  v8s qf0 = *(const v8s*)(Qp + (size_t)qrow * 64 + lg * 8);
  v8s qf1 = *(const v8s*)(Qp + (size_t)qrow * 64 + 32 + lg * 8);
  v8s ones;
  #pragma unroll
  for (int i = 0; i < 8; ++i) ones[i] = (short)0x3F80;
  float m = -3.0e38f;
  v4f acc[4] = {};
  v4f accl = {};
  const float THR = 11.5416f;   // 8 * log2(e)
  int slot0 = w * 128 + lane;
  int slot1 = slot0 + 64;
  int r0 = slot0 >> 3, c0 = slot0 & 7;
  int r1 = slot1 >> 3, c1 = slot1 & 7;
  int ko0 = r0 * 64 + ((c0 ^ (r0 & 7)) << 3);
  int ko1 = r1 * 64 + ((c1 ^ (r1 & 7)) << 3);
  size_t vo0 = (size_t)r0 * NN + ((c0 ^ (r0 & 7)) << 3);
  size_t vo1 = (size_t)r1 * NN + ((c1 ^ (r1 & 7)) << 3);

  #define STAGE(t, bf) do { \
    const short* Kt_ = Kp + (t) * 4096; \
    gload16(Kt_ + ko0, &Kl[bf][w * 1024]); \
    gload16(Kt_ + ko1, &Kl[bf][w * 1024 + 512]); \
    const short* Vt_ = Vp + (t) * 64; \
    gload16(Vt_ + vo0, &Vl[bf][w * 1024]); \
    gload16(Vt_ + vo1, &Vl[bf][w * 1024 + 512]); \
  } while (0)

  STAGE(0, 0);
  for (int kt = 0; kt < 64; ++kt) {
    int bf = kt & 1;
    if (kt < 63) {
      STAGE(kt + 1, bf ^ 1);
      asm volatile("s_waitcnt vmcnt(4)" ::: "memory");
    } else {
      asm volatile("s_waitcnt vmcnt(0)" ::: "memory");
    }
    __builtin_amdgcn_s_barrier();
    __builtin_amdgcn_sched_barrier(0);
    const short* Kb_ = Kl[bf];
    const short* Vb_ = Vl[bf];
    v4f st[4] = {};
    __builtin_amdgcn_s_setprio(1);
    #pragma unroll
    for (int c = 0; c < 4; ++c) {
      int kr = c * 16 + lr;
      v8s kf0 = *(const v8s*)(Kb_ + kr * 64 + ((lg ^ (kr & 7)) << 3));
      v8s kf1 = *(const v8s*)(Kb_ + kr * 64 + (((lg + 4) ^ (kr & 7)) << 3));
      st[c] = __builtin_amdgcn_mfma_f32_16x16x32_bf16(kf0, qf0, st[c], 0, 0, 0);
      st[c] = __builtin_amdgcn_mfma_f32_16x16x32_bf16(kf1, qf1, st[c], 0, 0, 0);
    }
    __builtin_amdgcn_s_setprio(0);
    // row max (lane owns q=lr), reduce over lg groups
    float t0 = fmaxf(fmaxf(st[0][0], st[0][1]), fmaxf(st[0][2], st[0][3]));
    float t1 = fmaxf(fmaxf(st[1][0], st[1][1]), fmaxf(st[1][2], st[1][3]));
    float t2 = fmaxf(fmaxf(st[2][0], st[2][1]), fmaxf(st[2][2], st[2][3]));
    float t3 = fmaxf(fmaxf(st[3][0], st[3][1]), fmaxf(st[3][2], st[3][3]));
    float pmax = fmaxf(fmaxf(t0, t1), fmaxf(t2, t3));
    pmax = fmaxf(pmax, __shfl_xor(pmax, 16, 64));
    pmax = fmaxf(pmax, __shfl_xor(pmax, 32, 64));
    // defer-max: rescale only when a row grew past THR
    if (__any(pmax - m > THR)) {
      float mn = fmaxf(m, pmax);
      float rr = fexp2(m - mn);
      m = mn;
      float rq[4];
      #pragma unroll
      for (int j = 0; j < 4; ++j) rq[j] = __shfl(rr, lg * 4 + j, 16);
      #pragma unroll
      for (int oc = 0; oc < 4; ++oc)
        #pragma unroll
        for (int j = 0; j < 4; ++j) acc[oc][j] *= rq[j];
      #pragma unroll
      for (int j = 0; j < 4; ++j) accl[j] *= rq[j];
    }
    // P = exp2(S - m), packed write to per-wave LDS
    #pragma unroll
    for (int c = 0; c < 4; ++c) {
      v4s pw;
      #pragma unroll
      for (int j = 0; j < 4; ++j) pw[j] = f2bs_fast(fexp2(st[c][j] - m));
      int o = c * 16 + lg * 4;
      int chunk = o >> 3, halfo = o & 7;
      *(v4s*)(&Pl[w][lr * 64 + ((chunk ^ (lr & 7)) << 3) + halfo]) = pw;
    }
    // PV + lsum-by-MFMA
    __builtin_amdgcn_s_setprio(1);
    #pragma unroll
    for (int s = 0; s < 2; ++s) {
      v8s pf = *(const v8s*)(&Pl[w][lr * 64 + (((s * 4 + lg) ^ (lr & 7)) << 3)]);
      accl = __builtin_amdgcn_mfma_f32_16x16x32_bf16(pf, ones, accl, 0, 0, 0);
      #pragma unroll
      for (int oc = 0; oc < 4; ++oc) {
        int dr = oc * 16 + lr;
        v8s vf = *(const v8s*)(Vb_ + dr * 64 + (((s * 4 + lg) ^ (dr & 7)) << 3));
        acc[oc] = __builtin_amdgcn_mfma_f32_16x16x32_bf16(pf, vf, acc[oc], 0, 0, 0);
      }
    }
    __builtin_amdgcn_s_setprio(0);
    __builtin_amdgcn_s_barrier();
    __builtin_amdgcn_sched_barrier(0);
  }
  #undef STAGE
  #pragma unroll
  for (int oc = 0; oc < 4; ++oc) {
    #pragma unroll
    for (int j = 0; j < 4; ++j) {
      int n = qt * 64 + w * 16 + lg * 4 + j;
      ctx[(size_t)(b * NN + n) * ND + h * NHD + oc * 16 + lr] = f2bs(acc[oc][j] / accl[j]);
    }
  }
}

// ---------------- K4: out-proj GEMM (M=16384,K=256,N=256) -> hbuf[:, 256:512]
__global__ __launch_bounds__(256)
void k_oproj(const short* __restrict__ ctx, const short* __restrict__ Wb,
             const float* __restrict__ bias, short* __restrict__ hbuf) {
  __shared__ short Al[64 * 32];
  __shared__ short Bl[64 * 32];
  int mt = blockIdx.x, nt = blockIdx.y, tid = threadIdx.x;
  int w = tid >> 6, lane = tid & 63, lg = lane >> 4, lr = lane & 15;
  int srow = tid >> 2, scol8 = (tid & 3) << 3;
  v4f acc[4] = {};
  for (int kt = 0; kt < 8; ++kt) {
    int k0 = kt * 32;
    v8s av = *(const v8s*)(ctx + (size_t)(mt * 64 + srow) * 256 + k0 + scol8);
    v8s bv = *(const v8s*)(Wb + (size_t)(nt * 64 + srow) * 256 + k0 + scol8);
    __syncthreads();
    *(v8s*)(Al + srow * 32 + (scol8 ^ ((srow & 3) << 3))) = av;
    *(v8s*)(Bl + srow * 32 + (scol8 ^ ((srow & 3) << 3))) = bv;
    __syncthreads();
    int ar = w * 16 + lr;
    v8s af = *(const v8s*)(Al + ar * 32 + ((lg * 8) ^ ((ar & 3) << 3)));
    #pragma unroll
    for (int c = 0; c < 4; ++c) {
      int br = c * 16 + lr;
      v8s bf = *(const v8s*)(Bl + br * 32 + ((lg * 8) ^ ((br & 3) << 3)));
      acc[c] = __builtin_amdgcn_mfma_f32_16x16x32_bf16(af, bf, acc[c], 0, 0, 0);
    }
  }
  #pragma unroll
  for (int c = 0; c < 4; ++c) {
    int gcol = nt * 64 + c * 16 + lr;
    float bb = bias[gcol];
    #pragma unroll
    for (int j = 0; j < 4; ++j) {
      int grow = mt * 64 + w * 16 + lg * 4 + j;
      hbuf[(size_t)grow * 512 + 256 + gcol] = f2bs(acc[c][j] + bb);
    }
  }
}

// ---------------- K5: ffn1 GEMM (M=16384,K=512,N=512) + bias + LN + GELU(tanh) -> h2 bf16
__global__ __launch_bounds__(256)
void k_ffn1(const short* __restrict__ hbuf, const short* __restrict__ Wb,
            const float* __restrict__ bias, const float* __restrict__ ln_g,
            const float* __restrict__ ln_b, short* __restrict__ h2) {
  __shared__ short Al[64 * 32];
  __shared__ short Bl[512 * 32];
  int mt = blockIdx.x, tid = threadIdx.x;
  int w = tid >> 6, lane = tid & 63, lg = lane >> 4, lr = lane & 15;
  int srow = tid >> 2, scol8 = (tid & 3) << 3;
  v4f acc[32] = {};
  for (int kt = 0; kt < 16; ++kt) {
    int k0 = kt * 32;
    v8s av = *(const v8s*)(hbuf + (size_t)(mt * 64 + srow) * 512 + k0 + scol8);
    v8s bvs[8];
    #pragma unroll
    for (int rr = 0; rr < 8; ++rr)
      bvs[rr] = *(const v8s*)(Wb + (size_t)(srow + rr * 64) * 512 + k0 + scol8);
    __syncthreads();
    *(v8s*)(Al + srow * 32 + (scol8 ^ ((srow & 3) << 3))) = av;
    #pragma unroll
    for (int rr = 0; rr < 8; ++rr) {
      int br = srow + rr * 64;
      *(v8s*)(Bl + br * 32 + (scol8 ^ ((br & 3) << 3))) = bvs[rr];
    }
    __syncthreads();
    int ar = w * 16 + lr;
    v8s af = *(const v8s*)(Al + ar * 32 + ((lg * 8) ^ ((ar & 3) << 3)));
    #pragma unroll
    for (int c = 0; c < 32; ++c) {
      int br = c * 16 + lr;
      v8s bf = *(const v8s*)(Bl + br * 32 + ((lg * 8) ^ ((br & 3) << 3)));
      acc[c] = __builtin_amdgcn_mfma_f32_16x16x32_bf16(af, bf, acc[c], 0, 0, 0);
    }
  }
  #pragma unroll
  for (int c = 0; c < 32; ++c) {
    float bb = bias[c * 16 + lr];
    #pragma unroll
    for (int j = 0; j < 4; ++j) acc[c][j] += bb;
  }
  float mu[4], rs[4];
  #pragma unroll
  for (int j = 0; j < 4; ++j) {
    float s = 0.f;
    #pragma unroll
    for (int c = 0; c < 32; ++c) s += acc[c][j];
    #pragma unroll
    for (int mk = 1; mk < 16; mk <<= 1) s += __shfl_xor(s, mk, 64);
    mu[j] = s * (1.0f / 512.0f);
  }
  #pragma unroll
  for (int j = 0; j < 4; ++j) {
    float s = 0.f;
    #pragma unroll
    for (int c = 0; c < 32; ++c) { float d = acc[c][j] - mu[j]; s += d * d; }
    #pragma unroll
    for (int mk = 1; mk < 16; mk <<= 1) s += __shfl_xor(s, mk, 64);
    rs[j] = rsqrtf(s * (1.0f / 512.0f) + 1e-5f);
  }
  #pragma unroll
  for (int c = 0; c < 32; ++c) {
    int col = c * 16 + lr;
    float g = ln_g[col], b2 = ln_b[col];
    #pragma unroll
    for (int j = 0; j < 4; ++j) {
      float y = (acc[c][j] - mu[j]) * rs[j] * g + b2;
      // GELU tanh-form: 0.5*y*(1+tanh(0.79788456*(y+0.044715*y^3)))
      float z = 0.7978845608f * (y + 0.044715f * y * y * y);
      float e = fexp2(2.88539008178f * z);        // e^{2z}
      float t = (e - 1.0f) * __builtin_amdgcn_rcpf(e + 1.0f);
      float ge = 0.5f * y * (1.0f + t);
      int grow = mt * 64 + w * 16 + lg * 4 + j;
      h2[(size_t)grow * 512 + col] = f2bs_fast(ge);
    }
  }
}

// ---------------- K6: ffn2 GEMM (M=16384,K=512,N=256) + bias + residual -> out fp32
__global__ __launch_bounds__(256)
void k_ffn2(const short* __restrict__ h2, const short* __restrict__ Wb,
            const float* __restrict__ bias, const float* __restrict__ desc,
            float* __restrict__ out) {
  __shared__ short Al[64 * 32];
  __shared__ short Bl[64 * 32];
  int mt = blockIdx.x, nt = blockIdx.y, tid = threadIdx.x;
  int w = tid >> 6, lane = tid & 63, lg = lane >> 4, lr = lane & 15;
  int srow = tid >> 2, scol8 = (tid & 3) << 3;
  v4f acc[4] = {};
  for (int kt = 0; kt < 16; ++kt) {
    int k0 = kt * 32;
    v8s av = *(const v8s*)(h2 + (size_t)(mt * 64 + srow) * 512 + k0 + scol8);
    v8s bv = *(const v8s*)(Wb + (size_t)(nt * 64 + srow) * 512 + k0 + scol8);
    __syncthreads();
    *(v8s*)(Al + srow * 32 + (scol8 ^ ((srow & 3) << 3))) = av;
    *(v8s*)(Bl + srow * 32 + (scol8 ^ ((srow & 3) << 3))) = bv;
    __syncthreads();
    int ar = w * 16 + lr;
    v8s af = *(const v8s*)(Al + ar * 32 + ((lg * 8) ^ ((ar & 3) << 3)));
    #pragma unroll
    for (int c = 0; c < 4; ++c) {
      int br = c * 16 + lr;
      v8s bf = *(const v8s*)(Bl + br * 32 + ((lg * 8) ^ ((br & 3) << 3)));
      acc[c] = __builtin_amdgcn_mfma_f32_16x16x32_bf16(af, bf, acc[c], 0, 0, 0);
    }
  }
  #pragma unroll
  for (int c = 0; c < 4; ++c) {
    int gcol = nt * 64 + c * 16 + lr;
    float bb = bias[gcol];
    #pragma unroll
    for (int j = 0; j < 4; ++j) {
      int grow = mt * 64 + w * 16 + lg * 4 + j;
      out[(size_t)grow * 256 + gcol] = desc[(size_t)grow * 256 + gcol] + acc[c][j] + bb;
    }
  }
}

extern "C" void kernel_launch(void* const* d_in, const int* in_sizes, int n_in,
                              void* d_out, int out_size, void* d_ws, size_t ws_size,
                              hipStream_t stream) {
  const float* desc   = (const float*)d_in[0];
  const float* kp     = (const float*)d_in[1];
  const float* Wqkv_w = (const float*)d_in[2];
  const float* Wqkv_b = (const float*)d_in[3];
  const float* out_w  = (const float*)d_in[4];
  const float* out_b  = (const float*)d_in[5];
  const float* ffn1_w = (const float*)d_in[6];
  const float* ffn1_b = (const float*)d_in[7];
  const float* ln_g   = (const float*)d_in[8];
  const float* ln_b   = (const float*)d_in[9];
  const float* ffn2_w = (const float*)d_in[10];
  const float* ffn2_b = (const float*)d_in[11];
  float* out = (float*)d_out;
  char* ws = (char*)d_ws;

  const size_t MB = 1024 * 1024;
  short* hbuf = (short*)(ws);                 // [16384][512] bf16 : 16MB (desc | message)
  short* Qb   = (short*)(ws + 16 * MB);       // [B,H,N,64] bf16 : 8MB
  short* Kb   = (short*)(ws + 24 * MB);       // 8MB
  short* Vt   = (short*)(ws + 32 * MB);       // [B,H,64,N] bf16 : 8MB (transposed V)
  short* ctxb = (short*)(ws + 40 * MB);       // [16384][256] bf16 : 8MB
  short* h2   = (short*)(ws + 16 * MB);       // reuses Qb/Kb (dead after attn)
  short* wbuf = (short*)(ws + 48 * MB);       // bf16 weights: 1.25MB
  short* wq = wbuf;                           // [768][256]
  short* wo = wbuf + 196608;                  // [256][256]
  short* w1 = wbuf + 262144;                  // [512][512]
  short* w2 = wbuf + 524288;                  // [256][512]

  k_wcast<<<dim3(320),       dim3(256), 0, stream>>>(Wqkv_w, out_w, ffn1_w, ffn2_w, wbuf);
  k_cast <<<dim3(4096),      dim3(256), 0, stream>>>(desc, hbuf);
  k_qkv  <<<dim3(256, 12),   dim3(256), 0, stream>>>(hbuf, wq, Wqkv_b, kp, Qb, Kb, Vt);
  k_attn <<<dim3(64, 16),    dim3(256), 0, stream>>>(Qb, Kb, Vt, ctxb);
  k_oproj<<<dim3(256, 4),    dim3(256), 0, stream>>>(ctxb, wo, out_b, hbuf);
  k_ffn1 <<<dim3(256),       dim3(256), 0, stream>>>(hbuf, w1, ffn1_b, ln_g, ln_b, h2);
  k_ffn2 <<<dim3(256, 4),    dim3(256), 0, stream>>>(h2, w2, ffn2_b, desc, out);
}